// Round 1
// baseline (271.758 us; speedup 1.0000x reference)
//
#include <hip/hip_runtime.h>
#include <math.h>

// B=1, H=32, S=2048, D=128, N_OUT=16, QMAX=7, EPS=1e-6
// Top-k indices never needed: only 16th (outlier threshold, kept exact) and
// 17th (scale) order statistics of |x| per slice.

typedef __bf16 bf16x8 __attribute__((ext_vector_type(8)));
typedef __bf16 bf16x4 __attribute__((ext_vector_type(4)));
typedef float f32x4 __attribute__((ext_vector_type(4)));

#define H 32
#define S 2048
#define D 128

// Branch-free descending top-17 insert: t[j] = med3(x, t[j-1], t[j]).
__device__ __forceinline__ void ins17(float t[17], float x) {
#pragma unroll
    for (int j = 16; j >= 1; --j) t[j] = __builtin_amdgcn_fmed3f(x, t[j - 1], t[j]);
    t[0] = fmaxf(t[0], x);
}

// ---------------------------------------------------------------------------
// Fused kernel 1:
//   blocks 0..255    : K partial top-17 per (h,ch) over a 256-token chunk.
//   blocks 256..1279 : V single-pass stats+apply+transpose for 64 rows.
// ---------------------------------------------------------------------------
#define VT_STRIDE 132   // 128 + 4 pad: LDS col reads are 2-way (free)

__global__ __launch_bounds__(256) void stats_kernel(const float* __restrict__ K,
                                                    const float* __restrict__ V,
                                                    float* __restrict__ cand,
                                                    __bf16* __restrict__ vT) {
    __shared__ char smem[65792] __attribute__((aligned(16)));
    if (blockIdx.x < 256) {
        float (*ml)[17] = (float (*)[17])smem;             // [128][17]
        const int h = blockIdx.x >> 3, tc = blockIdx.x & 7;
        const int ch = threadIdx.x & 127, ts = threadIdx.x >> 7;
        const float* p = K + ((size_t)h * S + tc * 256 + ts * 128) * D + ch;
        float ta[17], tb[17];
#pragma unroll
        for (int j = 0; j < 17; ++j) { ta[j] = -1.f; tb[j] = -1.f; }
#pragma unroll 8
        for (int i = 0; i < 64; ++i) {
            ins17(ta, fabsf(p[(size_t)i * D]));
            ins17(tb, fabsf(p[(size_t)(i + 64) * D]));
        }
#pragma unroll
        for (int j = 0; j < 17; ++j) ins17(ta, tb[j]);
        if (ts == 1) {
#pragma unroll
            for (int j = 0; j < 17; ++j) ml[ch][j] = ta[j];
        }
        __syncthreads();
        if (ts == 0) {
#pragma unroll
            for (int j = 0; j < 17; ++j) ins17(ta, ml[ch][j]);
            float* o = cand + ((size_t)(h * 128 + ch) * 8 + tc) * 17;
#pragma unroll
            for (int j = 0; j < 17; ++j) o[j] = ta[j];
        }
    } else {
        float (*vtile)[VT_STRIDE] = (float (*)[VT_STRIDE])smem;            // [64][132]
        float (*mlist)[3][17] = (float (*)[3][17])(smem + 33792);          // [64][3][17]
        float2* thrsc = (float2*)(smem + 46848);                           // [64]
        __bf16 (*otile)[72] = (__bf16 (*)[72])(smem + 47360);              // [128][72]

        const int lin = blockIdx.x - 256;
        const int h = lin >> 5;
        const int s0 = (lin & 31) * 64;
        const int tid = threadIdx.x;

        // phase 1: coalesced load of 64 rows x 128 ch into LDS
        const float4* gsrc = (const float4*)(V + ((size_t)h * S + s0) * D);
#pragma unroll
        for (int i = 0; i < 8; ++i) {
            const int idx = i * 256 + tid;
            const int row = idx >> 5, col4 = idx & 31;
            *(float4*)&vtile[row][col4 * 4] = gsrc[idx];
        }
        __syncthreads();

        // phase 2: per-row top-17; 4 threads/row x 32 channels, LDS merge.
        // Channel subset is STRIPED (seg + c*4): contiguous 32-blocks put all
        // 4 segs of a row on one bank (seg*32 % 32banks == 0) -> 8-way
        // conflict per read. Stripe makes banks 4*row+seg -> 2-way (free).
        // Union over segs is unchanged, so stats are identical.
        const int row = tid >> 2, seg = tid & 3;
        {
            float t0[17];
#pragma unroll
            for (int j = 0; j < 17; ++j) t0[j] = -1.f;
#pragma unroll 8
            for (int c = 0; c < 32; ++c) ins17(t0, fabsf(vtile[row][seg + c * 4]));
            if (seg != 0) {
#pragma unroll
                for (int j = 0; j < 17; ++j) mlist[row][seg - 1][j] = t0[j];
            }
            __syncthreads();
            if (seg == 0) {
#pragma unroll
                for (int s = 0; s < 3; ++s)
#pragma unroll
                    for (int j = 0; j < 17; ++j) ins17(t0, mlist[row][s][j]);
                thrsc[row] = make_float2(t0[15], fmaxf(t0[16], 1e-6f) / 7.0f);
            }
            __syncthreads();
        }

        // phase 3: apply + transpose (vtile -> bf16 otile[ch][s])
        const int wv = tid >> 6, lane = tid & 63;
#pragma unroll
        for (int g = 0; g < 2; ++g) {
            bf16x8 b0, b1;
#pragma unroll
            for (int it = 0; it < 8; ++it) {
                const int srel = wv * 16 + g * 8 + it;
                const float2 tc = thrsc[srel];
                const float a = vtile[srel][lane], b = vtile[srel][lane + 64];
                float o0, o1;
                if (fabsf(a) >= tc.x) o0 = a;
                else { float q = rintf(a / tc.y); q = fminf(fmaxf(q, -7.f), 7.f); o0 = q * tc.y; }
                if (fabsf(b) >= tc.x) o1 = b;
                else { float q = rintf(b / tc.y); q = fminf(fmaxf(q, -7.f), 7.f); o1 = q * tc.y; }
                b0[it] = (__bf16)o0;
                b1[it] = (__bf16)o1;
            }
            *(bf16x8*)&otile[lane][wv * 16 + g * 8] = b0;
            *(bf16x8*)&otile[lane + 64][wv * 16 + g * 8] = b1;
        }
        __syncthreads();
        const int dRow = tid >> 3, c3 = tid & 7;
#pragma unroll
        for (int i = 0; i < 4; ++i) {
            const int d = dRow + 32 * i;
            bf16x8 val = *(const bf16x8*)&otile[d][c3 * 8];
            *(bf16x8*)&vT[((size_t)h * D + d) * S + s0 + c3 * 8] = val;
        }
    }
}

// ---------------------------------------------------------------------------
// K stats phase 2: merge 8 partial lists -> thr16 + scale.
// r8: was 16 blocks (6% of GPU) with a fully-serial 187-insert chain per g.
// Now 64 blocks x 256 threads: 4 threads per g, each merges 2 partial lists
// (float2 loads, 34 inserts), LDS tree-merge (+51 on the leader). Critical
// path 187 -> 85 ins17, 16x more thread parallelism.
// ---------------------------------------------------------------------------
__global__ __launch_bounds__(256) void kmerge_kernel(const float* __restrict__ cand,
                                                     float2* __restrict__ ktab) {
    __shared__ float ml[64][3][17];
    const int tid = threadIdx.x;
    const int gl = tid >> 2, part = tid & 3;
    const int g = blockIdx.x * 64 + gl;                // (h*128+ch), 4096 total
    const float2* p = (const float2*)(cand + (size_t)g * 136 + part * 34);
    float t[17];
#pragma unroll
    for (int j = 0; j < 17; ++j) t[j] = -1.f;
#pragma unroll 4
    for (int i = 0; i < 17; ++i) {
        const float2 v = p[i];
        ins17(t, v.x);
        ins17(t, v.y);
    }
    if (part != 0) {
#pragma unroll
        for (int j = 0; j < 17; ++j) ml[gl][part - 1][j] = t[j];
    }
    __syncthreads();
    if (part == 0) {
#pragma unroll
        for (int s = 0; s < 3; ++s)
#pragma unroll
            for (int j = 0; j < 17; ++j) ins17(t, ml[gl][s][j]);
        ktab[g] = make_float2(t[15], fmaxf(t[16], 1e-6f) / 7.0f);
    }
}

// ---------------------------------------------------------------------------
// K apply: elementwise fake-quant, fully coalesced.
// ---------------------------------------------------------------------------
__global__ __launch_bounds__(256) void kapply_kernel(const float* __restrict__ K,
                                                     const float2* __restrict__ ktab,
                                                     __bf16* __restrict__ k_rec) {
    const size_t base = ((size_t)blockIdx.x * 256 + threadIdx.x) * 4;
    const int h = (int)(base >> 18);            // S*D = 2^18
    const int d0 = (int)(base & (D - 1));
    const float4 x = *(const float4*)(K + base);
    const float2* tp = ktab + h * D + d0;
    float xs[4] = {x.x, x.y, x.z, x.w};
    bf16x4 o;
#pragma unroll
    for (int c = 0; c < 4; ++c) {
        const float2 tc = tp[c];
        float v;
        if (fabsf(xs[c]) >= tc.x) v = xs[c];
        else {
            float q = rintf(xs[c] / tc.y);
            q = fminf(fmaxf(q, -7.f), 7.f);
            v = q * tc.y;
        }
        o[c] = (__bf16)v;
    }
    *(bf16x4*)(k_rec + base) = o;
}

// ---------------------------------------------------------------------------
// Causal flash attention, S^T form, LDS staging.
// r8 CHANGES:
//  (1) Pads replaced by T2 XOR swizzles (16B-group g' = g ^ (row&7) on Kl/Vt;
//      8B-slot s' = s ^ (2*(col&7)) on Pl). Every LDS access pattern is now
//      <=2-way on banks (hand-verified for staging writes, QK reads, Pl
//      writes/reads, PV Vt reads) — targets the 1.03e7 SQ_LDS_BANK_CONFLICT.
//  (2) LDS 45056 -> 40960 B exactly: 160KB/40KB = 4 blocks/CU (was 3).
//      __launch_bounds__(256,4); VGPR 84 fits the 128 cap with headroom.
// Carried from r7: prefetch issued after barrier #2 so global loads overlap
// the whole compute phase. Grid swizzle (r6): h pinned per XCD, qblk desc.
// ---------------------------------------------------------------------------
__global__ __launch_bounds__(256, 4) void attn_kernel(const float* __restrict__ Q,
                                                      const __bf16* __restrict__ k_rec,
                                                      const __bf16* __restrict__ vT,
                                                      float* __restrict__ out) {
    __shared__ __bf16 Kl[64][128];   // swizzled: 16B-group g' = g ^ (row&7), g in 0..15
    __shared__ __bf16 Vt[128][64];   // swizzled: 16B-group g' = g ^ (row&7), g in 0..7
    __shared__ __bf16 Pl[4][16][64]; // swizzled: 8B-slot  s' = s ^ (2*(col&7)), s in 0..15

    const int id = blockIdx.x;
    const int h = (id & 7) + 8 * ((id >> 3) & 3);
    const int qblk = 31 - (id >> 5);
    const int tid = threadIdx.x;
    const int wv = tid >> 6;
    const int lane = tid & 63;
    const int quad = lane >> 4;
    const int col = lane & 15;
    const int rowq16 = tid >> 4, chunk = tid & 15;   // K staging
    const int dRow = tid >> 3, c3 = tid & 7;         // V staging
    const int sw = col & 7;                          // reader-side row&7 (row = c*16+col)
    const int rqsw = rowq16 & 7;                     // Kl writer-side row&7
    const int dsw = dRow & 7;                        // Vt writer-side row&7
    const __bf16* kb = k_rec + (size_t)h * S * D;
    const __bf16* vb = vT + (size_t)h * D * S;
    const float kscale = 0.08838834764831845f * 1.4426950408889634f;  // 1/sqrt(D)*log2e
    const int q0 = qblk * 64;
    const int qloc = wv * 16 + col;

    // Q fragments (B-operand: n=col=q, k=quad*8+j), fp32 -> scale -> bf16
    bf16x8 qf[4];
    {
        const float* qbase = Q + ((size_t)h * S + q0 + wv * 16 + col) * D + quad * 8;
#pragma unroll
        for (int kk = 0; kk < 4; ++kk) {
            const float4 a = *(const float4*)(qbase + kk * 32);
            const float4 b = *(const float4*)(qbase + kk * 32 + 4);
            qf[kk] = (bf16x8){(__bf16)(a.x * kscale), (__bf16)(a.y * kscale),
                              (__bf16)(a.z * kscale), (__bf16)(a.w * kscale),
                              (__bf16)(b.x * kscale), (__bf16)(b.y * kscale),
                              (__bf16)(b.z * kscale), (__bf16)(b.w * kscale)};
        }
    }

    f32x4 oacc[8];
#pragma unroll
    for (int dt = 0; dt < 8; ++dt) oacc[dt] = (f32x4){0.f, 0.f, 0.f, 0.f};
    f32x4 lsum = (f32x4){0.f, 0.f, 0.f, 0.f};
    float mbase = -INFINITY;                 // normalization base (rebased rarely)

    // prefetch tile 0 into registers
    bf16x8 kreg[4], vreg[4];
#pragma unroll
    for (int i = 0; i < 4; ++i) {
        kreg[i] = *(const bf16x8*)&kb[(size_t)(rowq16 + 16 * i) * D + chunk * 8];
        vreg[i] = *(const bf16x8*)&vb[(size_t)(dRow + 32 * i) * S + c3 * 8];
    }

    for (int kt = 0; kt <= qblk; ++kt) {
        __syncthreads();                      // #1: prior tile's readers done
                                              //     (also drains in-flight prefetch)
#pragma unroll
        for (int i = 0; i < 4; ++i) {
            *(bf16x8*)&Kl[rowq16 + 16 * i][(chunk ^ rqsw) * 8] = kreg[i];
            *(bf16x8*)&Vt[dRow + 32 * i][(c3 ^ dsw) * 8] = vreg[i];
        }
        __syncthreads();                      // #2: LDS tiles visible (lgkm only)

        // issue next-tile prefetch NOW: overlaps the whole compute phase below
        if (kt < qblk) {
            const int kn = kt + 1;
#pragma unroll
            for (int i = 0; i < 4; ++i) {
                kreg[i] = *(const bf16x8*)&kb[(size_t)(kn * 64 + rowq16 + 16 * i) * D + chunk * 8];
                vreg[i] = *(const bf16x8*)&vb[(size_t)(dRow + 32 * i) * S + kn * 64 + c3 * 8];
            }
        }

        // S^T = K_tile(64x128) @ Q^T(128x16), already in log2 domain
        f32x4 sacc[4];
#pragma unroll
        for (int c = 0; c < 4; ++c) sacc[c] = (f32x4){0.f, 0.f, 0.f, 0.f};
#pragma unroll
        for (int kk = 0; kk < 4; ++kk)
#pragma unroll
            for (int c = 0; c < 4; ++c) {
                bf16x8 kfrag = *(const bf16x8*)&Kl[c * 16 + col][((kk * 4 + quad) ^ sw) * 8];
                sacc[c] = __builtin_amdgcn_mfma_f32_16x16x32_bf16(kfrag, qf[kk], sacc[c], 0, 0, 0);
            }

        // causal mask (diag tile only) + in-lane max
        float sv[4][4];
        float mt = -INFINITY;
        if (kt == qblk) {
#pragma unroll
            for (int c = 0; c < 4; ++c)
#pragma unroll
                for (int r = 0; r < 4; ++r) {
                    float val = sacc[c][r];
                    if (c * 16 + quad * 4 + r > qloc) val = -INFINITY;
                    sv[c][r] = val;
                    mt = fmaxf(mt, val);
                }
        } else {
#pragma unroll
            for (int c = 0; c < 4; ++c)
#pragma unroll
                for (int r = 0; r < 4; ++r) {
                    sv[c][r] = sacc[c][r];
                    mt = fmaxf(mt, sacc[c][r]);
                }
        }
        mt = fmaxf(mt, __shfl_xor(mt, 16));
        mt = fmaxf(mt, __shfl_xor(mt, 32));

        // threshold rebase: only when tile max exceeds base by >8 (rare)
        if (__ballot(mt > mbase + 8.f) != 0ull) {
            const float mnew = fmaxf(mbase, mt);
            const float alpha = exp2f(mbase - mnew);   // 1 for lanes not moving
            mbase = mnew;
            lsum *= alpha;
            float ar[4];
#pragma unroll
            for (int r = 0; r < 4; ++r) ar[r] = __shfl(alpha, quad * 20 + r);
#pragma unroll
            for (int dt = 0; dt < 8; ++dt)
#pragma unroll
                for (int r = 0; r < 4; ++r) oacc[dt][r] *= ar[r];
        }

        // exponentials + partial l sums (4 independent accumulators)
#pragma unroll
        for (int c = 0; c < 4; ++c) {
            float ls = lsum[c];
#pragma unroll
            for (int r = 0; r < 4; ++r) {
                const float pv = exp2f(sv[c][r] - mbase);
                sv[c][r] = pv;
                ls += pv;
            }
            lsum[c] = ls;
        }

        // P: pack 4 consecutive keys -> ds_write_b64 into Pl[q][key] (per-wave)
        // logical 8B-slot = c*4+quad; physical = slot ^ (2*sw)  [bijective/row]
#pragma unroll
        for (int c = 0; c < 4; ++c) {
            bf16x4 pk = {(__bf16)sv[c][0], (__bf16)sv[c][1], (__bf16)sv[c][2], (__bf16)sv[c][3]};
            *(bf16x4*)&Pl[wv][col][((c * 4 + quad) ^ (2 * sw)) * 4] = pk;
        }

        // O += P(16x64) @ V(64x128)
        // af logical slots {ks*8+2q, +1} -> physical pair ((ks*8+2q)^(2*sw)), contiguous
#pragma unroll
        for (int ks = 0; ks < 2; ++ks) {
            bf16x8 af = *(const bf16x8*)&Pl[wv][col][((ks * 8 + 2 * quad) ^ (2 * sw)) * 4];
#pragma unroll
            for (int dt = 0; dt < 8; ++dt) {
                bf16x8 bfrag = *(const bf16x8*)&Vt[dt * 16 + col][((ks * 4 + quad) ^ sw) * 8];
                oacc[dt] = __builtin_amdgcn_mfma_f32_16x16x32_bf16(af, bfrag, oacc[dt], 0, 0, 0);
            }
        }
    }

    // epilogue: fold partial l, cross-quad reduce, shuffle to O rows, store
    float l = (lsum[0] + lsum[1]) + (lsum[2] + lsum[3]);
    l += __shfl_xor(l, 16);
    l += __shfl_xor(l, 32);
    const float linv = 1.0f / l;
    float lr[4];
#pragma unroll
    for (int r = 0; r < 4; ++r) lr[r] = __shfl(linv, quad * 20 + r);
#pragma unroll
    for (int r = 0; r < 4; ++r) {
        const int qrow = q0 + wv * 16 + quad * 4 + r;
        float* ob = out + ((size_t)h * S + qrow) * D;
#pragma unroll
        for (int dt = 0; dt < 8; ++dt)
            ob[dt * 16 + col] = oacc[dt][r] * lr[r];
    }
}

// ---------------------------------------------------------------------------
extern "C" void kernel_launch(void* const* d_in, const int* in_sizes, int n_in,
                              void* d_out, int out_size, void* d_ws, size_t ws_size,
                              hipStream_t stream) {
    const float* Q = (const float*)d_in[0];
    const float* K = (const float*)d_in[1];
    const float* V = (const float*)d_in[2];
    float* out = (float*)d_out;

    char* ws = (char*)d_ws;
    const size_t nElem = (size_t)H * S * D;                  // 8,388,608
    __bf16* k_rec = (__bf16*)ws;                             // 16.78 MB
    __bf16* vT    = (__bf16*)(ws + nElem * 2);               // 16.78 MB
    float*  cand  = (float*)(ws + nElem * 4);                // 2.23 MB
    float2* ktab  = (float2*)(ws + nElem * 4 + (size_t)4096 * 136 * 4);   // 32 KB

    stats_kernel<<<dim3(1280), 256, 0, stream>>>(K, V, cand, vT);
    kmerge_kernel<<<dim3(64), 256, 0, stream>>>(cand, ktab);
    kapply_kernel<<<dim3(nElem / 1024), 256, 0, stream>>>(K, ktab, k_rec);
    attn_kernel<<<dim3(1024), 256, 0, stream>>>(Q, k_rec, vT, out);
}

// Round 2
// 246.183 us; speedup vs baseline: 1.1039x; 1.1039x over previous
//
#include <hip/hip_runtime.h>
#include <math.h>

// B=1, H=32, S=2048, D=128, N_OUT=16, QMAX=7, EPS=1e-6
// Top-k indices never needed: only 16th (outlier threshold, kept exact) and
// 17th (scale) order statistics of |x| per slice.

typedef __bf16 bf16x8 __attribute__((ext_vector_type(8)));
typedef __bf16 bf16x4 __attribute__((ext_vector_type(4)));
typedef float f32x4 __attribute__((ext_vector_type(4)));

#define H 32
#define S 2048
#define D 128

// Branch-free descending top-17 insert: t[j] = med3(x, t[j-1], t[j]).
__device__ __forceinline__ void ins17(float t[17], float x) {
#pragma unroll
    for (int j = 16; j >= 1; --j) t[j] = __builtin_amdgcn_fmed3f(x, t[j - 1], t[j]);
    t[0] = fmaxf(t[0], x);
}

// ---------------------------------------------------------------------------
// Fused kernel 1:
//   blocks 0..255    : K partial top-17 per (h,ch) over a 256-token chunk.
//   blocks 256..1279 : V single-pass stats+apply+transpose for 64 rows.
// ---------------------------------------------------------------------------
#define VT_STRIDE 132   // 128 + 4 pad: LDS col reads are 2-way (free)

__global__ __launch_bounds__(256) void stats_kernel(const float* __restrict__ K,
                                                    const float* __restrict__ V,
                                                    float* __restrict__ cand,
                                                    __bf16* __restrict__ vT) {
    __shared__ char smem[65792] __attribute__((aligned(16)));
    if (blockIdx.x < 256) {
        float (*ml)[17] = (float (*)[17])smem;             // [128][17]
        const int h = blockIdx.x >> 3, tc = blockIdx.x & 7;
        const int ch = threadIdx.x & 127, ts = threadIdx.x >> 7;
        const float* p = K + ((size_t)h * S + tc * 256 + ts * 128) * D + ch;
        float ta[17], tb[17];
#pragma unroll
        for (int j = 0; j < 17; ++j) { ta[j] = -1.f; tb[j] = -1.f; }
#pragma unroll 8
        for (int i = 0; i < 64; ++i) {
            ins17(ta, fabsf(p[(size_t)i * D]));
            ins17(tb, fabsf(p[(size_t)(i + 64) * D]));
        }
#pragma unroll
        for (int j = 0; j < 17; ++j) ins17(ta, tb[j]);
        if (ts == 1) {
#pragma unroll
            for (int j = 0; j < 17; ++j) ml[ch][j] = ta[j];
        }
        __syncthreads();
        if (ts == 0) {
#pragma unroll
            for (int j = 0; j < 17; ++j) ins17(ta, ml[ch][j]);
            float* o = cand + ((size_t)(h * 128 + ch) * 8 + tc) * 17;
#pragma unroll
            for (int j = 0; j < 17; ++j) o[j] = ta[j];
        }
    } else {
        float (*vtile)[VT_STRIDE] = (float (*)[VT_STRIDE])smem;            // [64][132]
        float (*mlist)[3][17] = (float (*)[3][17])(smem + 33792);          // [64][3][17]
        float2* thrsc = (float2*)(smem + 46848);                           // [64]
        __bf16 (*otile)[72] = (__bf16 (*)[72])(smem + 47360);              // [128][72]

        const int lin = blockIdx.x - 256;
        const int h = lin >> 5;
        const int s0 = (lin & 31) * 64;
        const int tid = threadIdx.x;

        // phase 1: coalesced load of 64 rows x 128 ch into LDS
        const float4* gsrc = (const float4*)(V + ((size_t)h * S + s0) * D);
#pragma unroll
        for (int i = 0; i < 8; ++i) {
            const int idx = i * 256 + tid;
            const int row = idx >> 5, col4 = idx & 31;
            *(float4*)&vtile[row][col4 * 4] = gsrc[idx];
        }
        __syncthreads();

        // phase 2: per-row top-17; 4 threads/row x 32 channels, LDS merge.
        // Channel subset is STRIPED (seg + c*4): contiguous 32-blocks put all
        // 4 segs of a row on one bank (seg*32 % 32banks == 0) -> 8-way
        // conflict per read. Stripe makes banks 4*row+seg -> 2-way (free).
        // Union over segs is unchanged, so stats are identical.
        const int row = tid >> 2, seg = tid & 3;
        {
            float t0[17];
#pragma unroll
            for (int j = 0; j < 17; ++j) t0[j] = -1.f;
#pragma unroll 8
            for (int c = 0; c < 32; ++c) ins17(t0, fabsf(vtile[row][seg + c * 4]));
            if (seg != 0) {
#pragma unroll
                for (int j = 0; j < 17; ++j) mlist[row][seg - 1][j] = t0[j];
            }
            __syncthreads();
            if (seg == 0) {
#pragma unroll
                for (int s = 0; s < 3; ++s)
#pragma unroll
                    for (int j = 0; j < 17; ++j) ins17(t0, mlist[row][s][j]);
                thrsc[row] = make_float2(t0[15], fmaxf(t0[16], 1e-6f) / 7.0f);
            }
            __syncthreads();
        }

        // phase 3: apply + transpose (vtile -> bf16 otile[ch][s])
        const int wv = tid >> 6, lane = tid & 63;
#pragma unroll
        for (int g = 0; g < 2; ++g) {
            bf16x8 b0, b1;
#pragma unroll
            for (int it = 0; it < 8; ++it) {
                const int srel = wv * 16 + g * 8 + it;
                const float2 tc = thrsc[srel];
                const float a = vtile[srel][lane], b = vtile[srel][lane + 64];
                float o0, o1;
                if (fabsf(a) >= tc.x) o0 = a;
                else { float q = rintf(a / tc.y); q = fminf(fmaxf(q, -7.f), 7.f); o0 = q * tc.y; }
                if (fabsf(b) >= tc.x) o1 = b;
                else { float q = rintf(b / tc.y); q = fminf(fmaxf(q, -7.f), 7.f); o1 = q * tc.y; }
                b0[it] = (__bf16)o0;
                b1[it] = (__bf16)o1;
            }
            *(bf16x8*)&otile[lane][wv * 16 + g * 8] = b0;
            *(bf16x8*)&otile[lane + 64][wv * 16 + g * 8] = b1;
        }
        __syncthreads();
        const int dRow = tid >> 3, c3 = tid & 7;
#pragma unroll
        for (int i = 0; i < 4; ++i) {
            const int d = dRow + 32 * i;
            bf16x8 val = *(const bf16x8*)&otile[d][c3 * 8];
            *(bf16x8*)&vT[((size_t)h * D + d) * S + s0 + c3 * 8] = val;
        }
    }
}

// ---------------------------------------------------------------------------
// K stats phase 2: merge 8 partial lists -> thr16 + scale.
// 64 blocks x 256 threads: 4 threads per g, each merges 2 partial lists
// (float2 loads, 34 inserts), LDS tree-merge (+51 on the leader).
// ---------------------------------------------------------------------------
__global__ __launch_bounds__(256) void kmerge_kernel(const float* __restrict__ cand,
                                                     float2* __restrict__ ktab) {
    __shared__ float ml[64][3][17];
    const int tid = threadIdx.x;
    const int gl = tid >> 2, part = tid & 3;
    const int g = blockIdx.x * 64 + gl;                // (h*128+ch), 4096 total
    const float2* p = (const float2*)(cand + (size_t)g * 136 + part * 34);
    float t[17];
#pragma unroll
    for (int j = 0; j < 17; ++j) t[j] = -1.f;
#pragma unroll 4
    for (int i = 0; i < 17; ++i) {
        const float2 v = p[i];
        ins17(t, v.x);
        ins17(t, v.y);
    }
    if (part != 0) {
#pragma unroll
        for (int j = 0; j < 17; ++j) ml[gl][part - 1][j] = t[j];
    }
    __syncthreads();
    if (part == 0) {
#pragma unroll
        for (int s = 0; s < 3; ++s)
#pragma unroll
            for (int j = 0; j < 17; ++j) ins17(t, ml[gl][s][j]);
        ktab[g] = make_float2(t[15], fmaxf(t[16], 1e-6f) / 7.0f);
    }
}

// ---------------------------------------------------------------------------
// K apply: elementwise fake-quant, fully coalesced.
// ---------------------------------------------------------------------------
__global__ __launch_bounds__(256) void kapply_kernel(const float* __restrict__ K,
                                                     const float2* __restrict__ ktab,
                                                     __bf16* __restrict__ k_rec) {
    const size_t base = ((size_t)blockIdx.x * 256 + threadIdx.x) * 4;
    const int h = (int)(base >> 18);            // S*D = 2^18
    const int d0 = (int)(base & (D - 1));
    const float4 x = *(const float4*)(K + base);
    const float2* tp = ktab + h * D + d0;
    float xs[4] = {x.x, x.y, x.z, x.w};
    bf16x4 o;
#pragma unroll
    for (int c = 0; c < 4; ++c) {
        const float2 tc = tp[c];
        float v;
        if (fabsf(xs[c]) >= tc.x) v = xs[c];
        else {
            float q = rintf(xs[c] / tc.y);
            q = fminf(fmaxf(q, -7.f), 7.f);
            v = q * tc.y;
        }
        o[c] = (__bf16)v;
    }
    *(bf16x4*)(k_rec + base) = o;
}

// ---------------------------------------------------------------------------
// Causal flash attention, S^T form, LDS staging.
// r9 CHANGE: revert launch bounds (256,4)->(256,3). r8's (256,4) made the
// backend target a 64-VGPR budget (8 waves/EU, not the requested 4) and SPILL:
// WRITE_SIZE 32768->85504 KB (+52 MB scratch stores), MfmaUtil 17->13%,
// dur +25%. With (256,3) the compiler's natural allocation is 84 VGPR (r7,
// no spill); occupancy is then LDS-limited: 160KB/40960B = 4 blocks/CU —
// the occupancy r8 wanted, without the spill tax.
// Kept from r8: T2 XOR swizzles on all LDS tiles (bank conflicts 1.03e7 ->
// 5.4e6, proven) + exact-40960B LDS footprint.
// Kept from r7: prefetch issued after barrier #2 (overlaps whole compute
// phase). Grid swizzle (r6): h pinned per XCD, qblk descending.
// ---------------------------------------------------------------------------
__global__ __launch_bounds__(256, 3) void attn_kernel(const float* __restrict__ Q,
                                                      const __bf16* __restrict__ k_rec,
                                                      const __bf16* __restrict__ vT,
                                                      float* __restrict__ out) {
    __shared__ __bf16 Kl[64][128];   // swizzled: 16B-group g' = g ^ (row&7), g in 0..15
    __shared__ __bf16 Vt[128][64];   // swizzled: 16B-group g' = g ^ (row&7), g in 0..7
    __shared__ __bf16 Pl[4][16][64]; // swizzled: 8B-slot  s' = s ^ (2*(col&7)), s in 0..15

    const int id = blockIdx.x;
    const int h = (id & 7) + 8 * ((id >> 3) & 3);
    const int qblk = 31 - (id >> 5);
    const int tid = threadIdx.x;
    const int wv = tid >> 6;
    const int lane = tid & 63;
    const int quad = lane >> 4;
    const int col = lane & 15;
    const int rowq16 = tid >> 4, chunk = tid & 15;   // K staging
    const int dRow = tid >> 3, c3 = tid & 7;         // V staging
    const int sw = col & 7;                          // reader-side row&7 (row = c*16+col)
    const int rqsw = rowq16 & 7;                     // Kl writer-side row&7
    const int dsw = dRow & 7;                        // Vt writer-side row&7
    const __bf16* kb = k_rec + (size_t)h * S * D;
    const __bf16* vb = vT + (size_t)h * D * S;
    const float kscale = 0.08838834764831845f * 1.4426950408889634f;  // 1/sqrt(D)*log2e
    const int q0 = qblk * 64;
    const int qloc = wv * 16 + col;

    // Q fragments (B-operand: n=col=q, k=quad*8+j), fp32 -> scale -> bf16
    bf16x8 qf[4];
    {
        const float* qbase = Q + ((size_t)h * S + q0 + wv * 16 + col) * D + quad * 8;
#pragma unroll
        for (int kk = 0; kk < 4; ++kk) {
            const float4 a = *(const float4*)(qbase + kk * 32);
            const float4 b = *(const float4*)(qbase + kk * 32 + 4);
            qf[kk] = (bf16x8){(__bf16)(a.x * kscale), (__bf16)(a.y * kscale),
                              (__bf16)(a.z * kscale), (__bf16)(a.w * kscale),
                              (__bf16)(b.x * kscale), (__bf16)(b.y * kscale),
                              (__bf16)(b.z * kscale), (__bf16)(b.w * kscale)};
        }
    }

    f32x4 oacc[8];
#pragma unroll
    for (int dt = 0; dt < 8; ++dt) oacc[dt] = (f32x4){0.f, 0.f, 0.f, 0.f};
    f32x4 lsum = (f32x4){0.f, 0.f, 0.f, 0.f};
    float mbase = -INFINITY;                 // normalization base (rebased rarely)

    // prefetch tile 0 into registers
    bf16x8 kreg[4], vreg[4];
#pragma unroll
    for (int i = 0; i < 4; ++i) {
        kreg[i] = *(const bf16x8*)&kb[(size_t)(rowq16 + 16 * i) * D + chunk * 8];
        vreg[i] = *(const bf16x8*)&vb[(size_t)(dRow + 32 * i) * S + c3 * 8];
    }

    for (int kt = 0; kt <= qblk; ++kt) {
        __syncthreads();                      // #1: prior tile's readers done
                                              //     (also drains in-flight prefetch)
#pragma unroll
        for (int i = 0; i < 4; ++i) {
            *(bf16x8*)&Kl[rowq16 + 16 * i][(chunk ^ rqsw) * 8] = kreg[i];
            *(bf16x8*)&Vt[dRow + 32 * i][(c3 ^ dsw) * 8] = vreg[i];
        }
        __syncthreads();                      // #2: LDS tiles visible (lgkm only)

        // issue next-tile prefetch NOW: overlaps the whole compute phase below
        if (kt < qblk) {
            const int kn = kt + 1;
#pragma unroll
            for (int i = 0; i < 4; ++i) {
                kreg[i] = *(const bf16x8*)&kb[(size_t)(kn * 64 + rowq16 + 16 * i) * D + chunk * 8];
                vreg[i] = *(const bf16x8*)&vb[(size_t)(dRow + 32 * i) * S + kn * 64 + c3 * 8];
            }
        }

        // S^T = K_tile(64x128) @ Q^T(128x16), already in log2 domain
        f32x4 sacc[4];
#pragma unroll
        for (int c = 0; c < 4; ++c) sacc[c] = (f32x4){0.f, 0.f, 0.f, 0.f};
#pragma unroll
        for (int kk = 0; kk < 4; ++kk)
#pragma unroll
            for (int c = 0; c < 4; ++c) {
                bf16x8 kfrag = *(const bf16x8*)&Kl[c * 16 + col][((kk * 4 + quad) ^ sw) * 8];
                sacc[c] = __builtin_amdgcn_mfma_f32_16x16x32_bf16(kfrag, qf[kk], sacc[c], 0, 0, 0);
            }

        // causal mask (diag tile only) + in-lane max
        float sv[4][4];
        float mt = -INFINITY;
        if (kt == qblk) {
#pragma unroll
            for (int c = 0; c < 4; ++c)
#pragma unroll
                for (int r = 0; r < 4; ++r) {
                    float val = sacc[c][r];
                    if (c * 16 + quad * 4 + r > qloc) val = -INFINITY;
                    sv[c][r] = val;
                    mt = fmaxf(mt, val);
                }
        } else {
#pragma unroll
            for (int c = 0; c < 4; ++c)
#pragma unroll
                for (int r = 0; r < 4; ++r) {
                    sv[c][r] = sacc[c][r];
                    mt = fmaxf(mt, sacc[c][r]);
                }
        }
        mt = fmaxf(mt, __shfl_xor(mt, 16));
        mt = fmaxf(mt, __shfl_xor(mt, 32));

        // threshold rebase: only when tile max exceeds base by >8 (rare)
        if (__ballot(mt > mbase + 8.f) != 0ull) {
            const float mnew = fmaxf(mbase, mt);
            const float alpha = exp2f(mbase - mnew);   // 1 for lanes not moving
            mbase = mnew;
            lsum *= alpha;
            float ar[4];
#pragma unroll
            for (int r = 0; r < 4; ++r) ar[r] = __shfl(alpha, quad * 20 + r);
#pragma unroll
            for (int dt = 0; dt < 8; ++dt)
#pragma unroll
                for (int r = 0; r < 4; ++r) oacc[dt][r] *= ar[r];
        }

        // exponentials + partial l sums (4 independent accumulators)
#pragma unroll
        for (int c = 0; c < 4; ++c) {
            float ls = lsum[c];
#pragma unroll
            for (int r = 0; r < 4; ++r) {
                const float pv = exp2f(sv[c][r] - mbase);
                sv[c][r] = pv;
                ls += pv;
            }
            lsum[c] = ls;
        }

        // P: pack 4 consecutive keys -> ds_write_b64 into Pl[q][key] (per-wave)
        // logical 8B-slot = c*4+quad; physical = slot ^ (2*sw)  [bijective/row]
#pragma unroll
        for (int c = 0; c < 4; ++c) {
            bf16x4 pk = {(__bf16)sv[c][0], (__bf16)sv[c][1], (__bf16)sv[c][2], (__bf16)sv[c][3]};
            *(bf16x4*)&Pl[wv][col][((c * 4 + quad) ^ (2 * sw)) * 4] = pk;
        }

        // O += P(16x64) @ V(64x128)
        // af logical slots {ks*8+2q, +1} -> physical pair ((ks*8+2q)^(2*sw)), contiguous
#pragma unroll
        for (int ks = 0; ks < 2; ++ks) {
            bf16x8 af = *(const bf16x8*)&Pl[wv][col][((ks * 8 + 2 * quad) ^ (2 * sw)) * 4];
#pragma unroll
            for (int dt = 0; dt < 8; ++dt) {
                bf16x8 bfrag = *(const bf16x8*)&Vt[dt * 16 + col][((ks * 4 + quad) ^ sw) * 8];
                oacc[dt] = __builtin_amdgcn_mfma_f32_16x16x32_bf16(af, bfrag, oacc[dt], 0, 0, 0);
            }
        }
    }

    // epilogue: fold partial l, cross-quad reduce, shuffle to O rows, store
    float l = (lsum[0] + lsum[1]) + (lsum[2] + lsum[3]);
    l += __shfl_xor(l, 16);
    l += __shfl_xor(l, 32);
    const float linv = 1.0f / l;
    float lr[4];
#pragma unroll
    for (int r = 0; r < 4; ++r) lr[r] = __shfl(linv, quad * 20 + r);
#pragma unroll
    for (int r = 0; r < 4; ++r) {
        const int qrow = q0 + wv * 16 + quad * 4 + r;
        float* ob = out + ((size_t)h * S + qrow) * D;
#pragma unroll
        for (int dt = 0; dt < 8; ++dt)
            ob[dt * 16 + col] = oacc[dt][r] * lr[r];
    }
}

// ---------------------------------------------------------------------------
extern "C" void kernel_launch(void* const* d_in, const int* in_sizes, int n_in,
                              void* d_out, int out_size, void* d_ws, size_t ws_size,
                              hipStream_t stream) {
    const float* Q = (const float*)d_in[0];
    const float* K = (const float*)d_in[1];
    const float* V = (const float*)d_in[2];
    float* out = (float*)d_out;

    char* ws = (char*)d_ws;
    const size_t nElem = (size_t)H * S * D;                  // 8,388,608
    __bf16* k_rec = (__bf16*)ws;                             // 16.78 MB
    __bf16* vT    = (__bf16*)(ws + nElem * 2);               // 16.78 MB
    float*  cand  = (float*)(ws + nElem * 4);                // 2.23 MB
    float2* ktab  = (float2*)(ws + nElem * 4 + (size_t)4096 * 136 * 4);   // 32 KB

    stats_kernel<<<dim3(1280), 256, 0, stream>>>(K, V, cand, vT);
    kmerge_kernel<<<dim3(64), 256, 0, stream>>>(cand, ktab);
    kapply_kernel<<<dim3(nElem / 1024), 256, 0, stream>>>(K, ktab, k_rec);
    attn_kernel<<<dim3(1024), 256, 0, stream>>>(Q, k_rec, vT, out);
}